// Round 2
// baseline (810.669 us; speedup 1.0000x reference)
//
#include <hip/hip_runtime.h>
#include <float.h>

#define D 64

// numpy pairwise_sum (n=64, contiguous): 8 stride-interleaved accumulators,
// combined as ((r0+r1)+(r2+r3))+((r4+r5)+(r6+r7)). Squares rounded separately
// (numpy materializes x*x then sums) -> use _rn intrinsics to block contraction.
__device__ __forceinline__ float np_sum_sq_64(const float* v) {
  float s[8];
#pragma unroll
  for (int j = 0; j < 8; ++j) s[j] = __fmul_rn(v[j], v[j]);
#pragma unroll
  for (int b = 1; b < 8; ++b) {
#pragma unroll
    for (int j = 0; j < 8; ++j)
      s[j] = __fadd_rn(s[j], __fmul_rn(v[8 * b + j], v[8 * b + j]));
  }
  float t01 = __fadd_rn(s[0], s[1]);
  float t23 = __fadd_rn(s[2], s[3]);
  float t45 = __fadd_rn(s[4], s[5]);
  float t67 = __fadd_rn(s[6], s[7]);
  return __fadd_rn(__fadd_rn(t01, t23), __fadd_rn(t45, t67));
}

// ---------------- Kernel A: c2[k] = np.sum(codebook[k]^2) bit-faithful
__global__ __launch_bounds__(256) void vq_prep(const float* __restrict__ codebook,
                                               float* __restrict__ c2, int K) {
  int k = blockIdx.x * 256 + threadIdx.x;
  if (k < K) {
    float row[D];
    const float4* cp = (const float4*)(codebook + (size_t)k * D);
#pragma unroll
    for (int i = 0; i < 16; ++i) {
      float4 v = cp[i];
      row[4 * i] = v.x; row[4 * i + 1] = v.y;
      row[4 * i + 2] = v.z; row[4 * i + 3] = v.w;
    }
    c2[k] = np_sum_sq_64(row);
  }
}

// ---------------- Kernel B: fp32-faithful argmin, 2 rows/thread.
// Replicates np: dist = (r2 + c2_k) - 2*sgemm_dot (sequential-k fp32 FMA chain),
// argmin = first index of min (strict < scan).
__global__ __launch_bounds__(256, 2) void vq_argmin(
    const float* __restrict__ residual, const float* __restrict__ codebook,
    const float* __restrict__ c2, float* __restrict__ codes_f,
    int N, int K) {
  int t = blockIdx.x * 256 + threadIdx.x;
  int na = t * 2, nb = t * 2 + 1;
  if (na >= N) return;
  bool has_b = (nb < N);

  float ra[D], rb[D];
  {
    const float4* pa = (const float4*)(residual + (size_t)na * D);
    const float4* pb = (const float4*)(residual + (size_t)(has_b ? nb : na) * D);
#pragma unroll
    for (int i = 0; i < 16; ++i) {
      float4 va = pa[i], vb = pb[i];
      ra[4 * i] = va.x; ra[4 * i + 1] = va.y; ra[4 * i + 2] = va.z; ra[4 * i + 3] = va.w;
      rb[4 * i] = vb.x; rb[4 * i + 1] = vb.y; rb[4 * i + 2] = vb.z; rb[4 * i + 3] = vb.w;
    }
  }

  float r2a = np_sum_sq_64(ra);
  float r2b = np_sum_sq_64(rb);

  float mina = FLT_MAX, minb = FLT_MAX;
  int ia = 0, ib = 0;

  for (int k = 0; k < K; ++k) {
    const float* cp = codebook + (size_t)k * D;  // wave-uniform -> scalar loads
    float ck = c2[k];
    float ma = 0.f, mb = 0.f;  // sgemm: acc=0, sequential fma over k-dim
#pragma unroll
    for (int d = 0; d < D; ++d) {
      float c = cp[d];
      ma = __fmaf_rn(ra[d], c, ma);
      mb = __fmaf_rn(rb[d], c, mb);
    }
    // np: ((r2 + c2) - (2.0 * M)), elementwise fp32
    float da = __fsub_rn(__fadd_rn(r2a, ck), __fmul_rn(2.0f, ma));
    float db = __fsub_rn(__fadd_rn(r2b, ck), __fmul_rn(2.0f, mb));

    if (da < mina) { mina = da; ia = k; }   // strict < => first-min, like np.argmin
    if (db < minb) { minb = db; ib = k; }
  }

  codes_f[na] = (float)ia;
  if (has_b) codes_f[nb] = (float)ib;
}

// ---------------- Kernel C: quantized[n][d] = codebook[code[n]][d], coalesced.
__global__ __launch_bounds__(256) void vq_gather(
    const float* __restrict__ codebook, const float* __restrict__ codes_f,
    float* __restrict__ out_q, long long total) {
  long long e = (long long)blockIdx.x * 256 + threadIdx.x;
  if (e >= total) return;
  long long n = e >> 6;
  int d = (int)(e & 63);
  int c = (int)codes_f[n];
  out_q[e] = codebook[((size_t)c << 6) + d];
}

extern "C" void kernel_launch(void* const* d_in, const int* in_sizes, int n_in,
                              void* d_out, int out_size, void* d_ws, size_t ws_size,
                              hipStream_t stream) {
  const float* residual = (const float*)d_in[0];
  const float* codebook = (const float*)d_in[1];
  int N = in_sizes[0] / D;
  int K = in_sizes[1] / D;

  float* out_q = (float*)d_out;
  float* codes_f = out_q + (size_t)N * D;  // codes chunk, stored as float32 values

  float* c2 = (float*)d_ws;  // K floats

  vq_prep<<<(K + 255) / 256, 256, 0, stream>>>(codebook, c2, K);

  int nthreads = (N + 1) / 2;
  vq_argmin<<<(nthreads + 255) / 256, 256, 0, stream>>>(
      residual, codebook, c2, codes_f, N, K);

  long long total = (long long)N * D;
  vq_gather<<<(unsigned int)((total + 255) / 256), 256, 0, stream>>>(
      codebook, codes_f, out_q, total);
}

// Round 3
// 485.174 us; speedup vs baseline: 1.6709x; 1.6709x over previous
//
#include <hip/hip_runtime.h>
#include <float.h>

#define D 64
#define MARGIN 6e-5f

typedef float f32x4 __attribute__((ext_vector_type(4)));
typedef short bf16x8 __attribute__((ext_vector_type(8)));

// ---- bf16 round-to-nearest-even split helpers (bit-level, no lib deps)
__device__ __forceinline__ unsigned short bf16_rn(float f) {
  unsigned int u = __float_as_uint(f);
  u += 0x7fffu + ((u >> 16) & 1u);
  return (unsigned short)(u >> 16);
}
__device__ __forceinline__ float bf16_to_f(unsigned short h) {
  return __uint_as_float(((unsigned int)h) << 16);
}

// numpy pairwise_sum (n=64): 8 stride-interleaved accumulators,
// tree combine; squares rounded separately (verified bit-exact in round 2).
__device__ __forceinline__ float np_sum_sq_64(const float* v) {
  float s[8];
#pragma unroll
  for (int j = 0; j < 8; ++j) s[j] = __fmul_rn(v[j], v[j]);
#pragma unroll
  for (int b = 1; b < 8; ++b) {
#pragma unroll
    for (int j = 0; j < 8; ++j)
      s[j] = __fadd_rn(s[j], __fmul_rn(v[8 * b + j], v[8 * b + j]));
  }
  float t01 = __fadd_rn(s[0], s[1]);
  float t23 = __fadd_rn(s[2], s[3]);
  float t45 = __fadd_rn(s[4], s[5]);
  float t67 = __fadd_rn(s[6], s[7]);
  return __fadd_rn(__fadd_rn(t01, t23), __fadd_rn(t45, t67));
}

// ---------------- Kernel A: per-code c2 (np-faithful) + bf16 hi/lo codebook split
__global__ __launch_bounds__(256) void vq_prep(
    const float* __restrict__ cb, unsigned short* __restrict__ cbh,
    unsigned short* __restrict__ cbl, float* __restrict__ c2,
    unsigned int* __restrict__ flag_count, int K) {
  if (blockIdx.x == 0 && threadIdx.x == 0) *flag_count = 0u;
  int k = blockIdx.x * 256 + threadIdx.x;
  if (k >= K) return;
  float row[D];
  const float4* cp = (const float4*)(cb + (size_t)k * D);
#pragma unroll
  for (int i = 0; i < 16; ++i) {
    float4 v = cp[i];
    row[4 * i] = v.x; row[4 * i + 1] = v.y;
    row[4 * i + 2] = v.z; row[4 * i + 3] = v.w;
  }
#pragma unroll
  for (int i = 0; i < 16; ++i) {
    unsigned short h[4], l[4];
#pragma unroll
    for (int e = 0; e < 4; ++e) {
      float f = row[4 * i + e];
      h[e] = bf16_rn(f);
      l[e] = bf16_rn(f - bf16_to_f(h[e]));
    }
    unsigned int h01 = (unsigned int)h[0] | ((unsigned int)h[1] << 16);
    unsigned int h23 = (unsigned int)h[2] | ((unsigned int)h[3] << 16);
    unsigned int l01 = (unsigned int)l[0] | ((unsigned int)l[1] << 16);
    unsigned int l23 = (unsigned int)l[2] | ((unsigned int)l[3] << 16);
    *(uint2*)(cbh + (size_t)k * D + 4 * i) = make_uint2(h01, h23);
    *(uint2*)(cbl + (size_t)k * D + 4 * i) = make_uint2(l01, l23);
  }
  c2[k] = np_sum_sq_64(row);
}

// ---------------- Kernel B: MFMA screen. wg=256(4 waves) x 64 rows; 16 chunks of 64 codes.
// A (residual) split->LDS in fragment-permuted layout once; A-frags in registers.
// B-frags straight from global pre-split codebook (L2-resident). No barrier in main loop.
__global__ __launch_bounds__(256) void vq_screen(
    const float* __restrict__ residual, const unsigned short* __restrict__ cbh,
    const unsigned short* __restrict__ cbl, const float* __restrict__ c2,
    float* __restrict__ codes_f, unsigned int* __restrict__ flag_count,
    int* __restrict__ flag_list, int N, int K) {
  __shared__ unsigned short smem[8192];  // 16 KB: [seg(2)][blk(8)][lane(64)*8 shorts]
  unsigned short* ldsAh = smem;
  unsigned short* ldsAl = smem + 4096;

  int tid = threadIdx.x;
  int rowbase = blockIdx.x * 64;

  // ---- stage: 64 rows x 64 dims fp32 -> hi/lo bf16, fragment-permuted
  for (int i = tid; i < 1024; i += 256) {  // i = float4 index: r = i>>4, d0 = (i&15)*4
    int r = i >> 4, d0 = (i & 15) * 4;
    float4 v = *(const float4*)(residual + (size_t)(rowbase + r) * D + d0);
    float vf[4] = {v.x, v.y, v.z, v.w};
    unsigned short h[4], l[4];
#pragma unroll
    for (int e = 0; e < 4; ++e) {
      h[e] = bf16_rn(vf[e]);
      l[e] = bf16_rn(vf[e] - bf16_to_f(h[e]));
    }
    int tile = r >> 4, rr = r & 15;
    int kblk = d0 >> 5, kk = d0 & 31;
    int lanep = rr + 16 * (kk >> 3);
    int off = ((tile * 2 + kblk) * 64 + lanep) * 8 + (kk & 7);  // shorts; (kk&7) in {0,4}
    *(uint2*)(ldsAh + off) = make_uint2((unsigned int)h[0] | ((unsigned int)h[1] << 16),
                                        (unsigned int)h[2] | ((unsigned int)h[3] << 16));
    *(uint2*)(ldsAl + off) = make_uint2((unsigned int)l[0] | ((unsigned int)l[1] << 16),
                                        (unsigned int)l[2] | ((unsigned int)l[3] << 16));
  }
  __syncthreads();

  int w = tid >> 6, lane = tid & 63;
  int lane15 = lane & 15, lq = lane >> 4;

  // A fragments -> registers (ds_read_b128 at lane*16B, conflict-free)
  bf16x8 ah[4][2], al[4][2];
#pragma unroll
  for (int t = 0; t < 4; ++t)
#pragma unroll
    for (int kb = 0; kb < 2; ++kb) {
      ah[t][kb] = *(const bf16x8*)(ldsAh + ((t * 2 + kb) * 64 + lane) * 8);
      al[t][kb] = *(const bf16x8*)(ldsAl + ((t * 2 + kb) * 64 + lane) * 8);
    }

  float m1[4][4], m2[4][4];
  int bi[4][4];
#pragma unroll
  for (int t = 0; t < 4; ++t)
#pragma unroll
    for (int j = 0; j < 4; ++j) { m1[t][j] = FLT_MAX; m2[t][j] = FLT_MAX; bi[t][j] = 0; }

  int code = w * 16 + lane15;  // this lane's code column; += 64 per chunk
  const unsigned short* ph = cbh + (size_t)code * D + lq * 8;
  const unsigned short* pl = cbl + (size_t)code * D + lq * 8;

  for (int cc = 0; cc < 16; ++cc) {
    bf16x8 ch0 = *(const bf16x8*)(ph);
    bf16x8 ch1 = *(const bf16x8*)(ph + 32);
    bf16x8 cl0 = *(const bf16x8*)(pl);
    bf16x8 cl1 = *(const bf16x8*)(pl + 32);
    float c2v = c2[code];

#pragma unroll
    for (int t = 0; t < 4; ++t) {
      f32x4 a = {0.f, 0.f, 0.f, 0.f};
      a = __builtin_amdgcn_mfma_f32_16x16x32_bf16(ah[t][0], ch0, a, 0, 0, 0);
      a = __builtin_amdgcn_mfma_f32_16x16x32_bf16(ah[t][1], ch1, a, 0, 0, 0);
      a = __builtin_amdgcn_mfma_f32_16x16x32_bf16(al[t][0], ch0, a, 0, 0, 0);
      a = __builtin_amdgcn_mfma_f32_16x16x32_bf16(al[t][1], ch1, a, 0, 0, 0);
      a = __builtin_amdgcn_mfma_f32_16x16x32_bf16(ah[t][0], cl0, a, 0, 0, 0);
      a = __builtin_amdgcn_mfma_f32_16x16x32_bf16(ah[t][1], cl1, a, 0, 0, 0);
#pragma unroll
      for (int j = 0; j < 4; ++j) {
        float s = __builtin_fmaf(-2.f, a[j], c2v);
        bool lt = s < m1[t][j];
        m2[t][j] = fminf(m2[t][j], fmaxf(m1[t][j], s));
        m1[t][j] = lt ? s : m1[t][j];
        bi[t][j] = lt ? code : bi[t][j];
      }
    }
    code += 64;
    ph += 64 * D;
    pl += 64 * D;
  }

  // reduce across the 16 code-columns (lanes differing in bits 0..3)
#pragma unroll
  for (int dlt = 1; dlt < 16; dlt <<= 1) {
#pragma unroll
    for (int t = 0; t < 4; ++t)
#pragma unroll
      for (int j = 0; j < 4; ++j) {
        float om1 = __shfl_xor(m1[t][j], dlt, 64);
        float om2 = __shfl_xor(m2[t][j], dlt, 64);
        int obi = __shfl_xor(bi[t][j], dlt, 64);
        float nm2 = fminf(fminf(m2[t][j], om2), fmaxf(fminf(m1[t][j], om1) == m1[t][j] ? om1 : m1[t][j], fminf(m1[t][j], om1)));
        // nm2 = min(m2a, m2b, max(m1a, m1b)) -- write it plainly:
        nm2 = fminf(fminf(m2[t][j], om2), fmaxf(m1[t][j], om1));
        bool take = (om1 < m1[t][j]) || (om1 == m1[t][j] && obi < bi[t][j]);
        m1[t][j] = take ? om1 : m1[t][j];
        bi[t][j] = take ? obi : bi[t][j];
        m2[t][j] = nm2;
      }
  }

  __syncthreads();  // done reading A-LDS; reuse for cross-wave reduce
  float* red = (float*)smem;  // [wave][row(64)][3]
  if (lane15 == 0) {
#pragma unroll
    for (int t = 0; t < 4; ++t)
#pragma unroll
      for (int j = 0; j < 4; ++j) {
        int r = t * 16 + lq * 4 + j;
        red[(w * 64 + r) * 3 + 0] = m1[t][j];
        red[(w * 64 + r) * 3 + 1] = m2[t][j];
        red[(w * 64 + r) * 3 + 2] = __int_as_float(bi[t][j]);
      }
  }
  __syncthreads();
  if (tid < 64) {
    float M1 = FLT_MAX, M2 = FLT_MAX;
    int BI = 0x7fffffff;
#pragma unroll
    for (int wv = 0; wv < 4; ++wv) {
      float om1 = red[(wv * 64 + tid) * 3 + 0];
      float om2 = red[(wv * 64 + tid) * 3 + 1];
      int obi = __float_as_int(red[(wv * 64 + tid) * 3 + 2]);
      float nm2 = fminf(fminf(M2, om2), fmaxf(M1, om1));
      bool take = (om1 < M1) || (om1 == M1 && obi < BI);
      M1 = take ? om1 : M1;
      BI = take ? obi : BI;
      M2 = nm2;
    }
    codes_f[rowbase + tid] = (float)BI;
    if (M2 - M1 < MARGIN) {
      unsigned int s = atomicAdd(flag_count, 1u);
      flag_list[s] = rowbase + tid;
    }
  }
}

// ---------------- Kernel C: exact np-faithful rescore of flagged rows.
// One wave per row; lane handles codes lane+64j (ascending -> first-min per lane).
__global__ __launch_bounds__(256) void vq_rescore(
    const float* __restrict__ residual, const float* __restrict__ codebook,
    const float* __restrict__ c2, float* __restrict__ codes_f,
    const unsigned int* __restrict__ flag_count, const int* __restrict__ flag_list,
    int K) {
  unsigned int cnt = *flag_count;
  int wv = threadIdx.x >> 6, lane = threadIdx.x & 63;
  for (unsigned int j = blockIdx.x * 4 + wv; j < cnt; j += gridDim.x * 4) {
    int n = flag_list[j];
    float rr[D];
    const float4* rp = (const float4*)(residual + (size_t)n * D);
#pragma unroll
    for (int i = 0; i < 16; ++i) {
      float4 v = rp[i];
      rr[4 * i] = v.x; rr[4 * i + 1] = v.y; rr[4 * i + 2] = v.z; rr[4 * i + 3] = v.w;
    }
    float r2 = np_sum_sq_64(rr);
    float best = FLT_MAX;
    int bk = 0x7fffffff;
    for (int q = 0; q < 16; ++q) {
      int k = lane + 64 * q;
      const float* cp = codebook + (size_t)k * D;
      float m = 0.f;
#pragma unroll
      for (int d = 0; d < D; ++d) m = __fmaf_rn(rr[d], cp[d], m);
      float dist = __fsub_rn(__fadd_rn(r2, c2[k]), __fmul_rn(2.0f, m));
      if (dist < best) { best = dist; bk = k; }
    }
#pragma unroll
    for (int off = 32; off > 0; off >>= 1) {
      float ob = __shfl_down(best, off, 64);
      int oi = __shfl_down(bk, off, 64);
      if (ob < best || (ob == best && oi < bk)) { best = ob; bk = oi; }
    }
    if (lane == 0) codes_f[n] = (float)bk;
  }
}

// ---------------- Kernel D: quantized[n][d] = codebook[code[n]][d]
__global__ __launch_bounds__(256) void vq_gather(
    const float* __restrict__ codebook, const float* __restrict__ codes_f,
    float* __restrict__ out_q, long long total) {
  long long e = (long long)blockIdx.x * 256 + threadIdx.x;
  if (e >= total) return;
  long long n = e >> 6;
  int d = (int)(e & 63);
  int c = (int)codes_f[n];
  out_q[e] = codebook[((size_t)c << 6) + d];
}

extern "C" void kernel_launch(void* const* d_in, const int* in_sizes, int n_in,
                              void* d_out, int out_size, void* d_ws, size_t ws_size,
                              hipStream_t stream) {
  const float* residual = (const float*)d_in[0];
  const float* codebook = (const float*)d_in[1];
  int N = in_sizes[0] / D;
  int K = in_sizes[1] / D;

  float* out_q = (float*)d_out;
  float* codes_f = out_q + (size_t)N * D;

  // workspace layout (bytes): c2[K] | cbh[K*D] | cbl[K*D] | flag_count | flag_list[N]
  char* ws = (char*)d_ws;
  float* c2 = (float*)ws;                                    // K*4 B
  unsigned short* cbh = (unsigned short*)(ws + (size_t)K * 4);           // K*D*2 B
  unsigned short* cbl = (unsigned short*)(ws + (size_t)K * 4 + (size_t)K * D * 2);
  unsigned int* flag_count = (unsigned int*)(ws + (size_t)K * 4 + (size_t)K * D * 4);
  int* flag_list = (int*)(flag_count + 1);

  vq_prep<<<(K + 255) / 256, 256, 0, stream>>>(codebook, cbh, cbl, c2, flag_count, K);

  vq_screen<<<N / 64, 256, 0, stream>>>(residual, cbh, cbl, c2, codes_f,
                                        flag_count, flag_list, N, K);

  vq_rescore<<<1024, 256, 0, stream>>>(residual, codebook, c2, codes_f,
                                       flag_count, flag_list, K);

  long long total = (long long)N * D;
  vq_gather<<<(unsigned int)((total + 255) / 256), 256, 0, stream>>>(
      codebook, codes_f, out_q, total);
}